// Round 5
// baseline (242.895 us; speedup 1.0000x reference)
//
#include <hip/hip_runtime.h>
#include <hip/hip_fp16.h>

#define M_TOTAL 512
#define N_TOTAL 11008
#define K_TOTAL 4096
#define BM 64
#define BN 64
#define BK 64
#define NT (K_TOTAL / BK)  // 64
#define LDK 72             // fallback kernel's padded stride

typedef short bf16x8 __attribute__((ext_vector_type(8)));
typedef float f32x4 __attribute__((ext_vector_type(4)));

// pack two fp32 into two bf16 (round-half-up) -> uint32 (f0 in low 16)
__device__ __forceinline__ unsigned int pack2_bf16(float f0, float f1) {
    unsigned int u0 = __builtin_bit_cast(unsigned int, f0) + 0x8000u;
    unsigned int u1 = __builtin_bit_cast(unsigned int, f1) + 0x8000u;
    return (u0 >> 16) | (u1 & 0xFFFF0000u);
}

// async global->LDS 16B DMA (LDS dest must be wave-uniform base + lane*16)
__device__ __forceinline__ void async_ld16(void* lds, const void* g) {
    __builtin_amdgcn_global_load_lds(
        (const __attribute__((address_space(1))) unsigned int*)g,
        (__attribute__((address_space(3))) unsigned int*)lds, 16, 0, 0);
}

// Detect delivered dtype of weight_norm: 0=f32, 1=f16, 2=bf16.
// PARALLEL: one element per lane, ballot-reduce (r4's serial version cost ~80us).
__global__ void detect_norm_dtype(const void* __restrict__ wn, int* __restrict__ mode_out) {
    const int i = threadIdx.x;  // 64 lanes, 1 wave
    const unsigned short* u16 = (const unsigned short*)wn;
    const float* f32p = (const float*)wn;
    const float vb = __builtin_bit_cast(float, (unsigned int)u16[i] << 16);
    const float vh = __half2float(__builtin_bit_cast(__half, u16[i]));
    const float vf = f32p[i];
    const unsigned long long mb = __ballot(vb > 0.005f && vb < 0.12f);
    const unsigned long long mh = __ballot(vh > 0.005f && vh < 0.12f);
    const unsigned long long mf = __ballot(vf > 0.005f && vf < 0.12f);
    if (i == 0)
        *mode_out = (mb == ~0ull) ? 2 : ((mh == ~0ull) ? 1 : 0);
    (void)mf;
}

// one-shot x fp32 -> bf16
__global__ void __launch_bounds__(256)
convert_x_kernel(const float* __restrict__ x, unsigned short* __restrict__ xb) {
    const int i = (blockIdx.x * 256 + threadIdx.x) * 4;
    const float4 v = *(const float4*)&x[i];
    *(uint2*)&xb[i] = make_uint2(pack2_bf16(v.x, v.y), pack2_bf16(v.z, v.w));
}

// ---------------- pipelined main kernel (64x64 tile, 5 blocks/CU) ----------------
__global__ void __launch_bounds__(256, 5)
l3b_gemm_pipe(const unsigned short* __restrict__ xb, const int* __restrict__ wq,
              const void* __restrict__ wnorm, const float* __restrict__ bias,
              float* __restrict__ out, const int* __restrict__ mode_ptr)
{
    // XOR-swizzled, unpadded: row stride 64 el (128 B); 16-B chunk p of row r
    // holds logical chunk p ^ (r & 7).
    __shared__ unsigned short As[2][BM * 64];  // 8 KB x2
    __shared__ unsigned short Bs[2][BN * 64];  // 8 KB x2  -> 32 KB total

    const int mode = *mode_ptr;
    const int tid  = threadIdx.x;

    // XCD-aware swizzle: HW round-robins blockIdx across 8 XCDs. Map so each
    // XCD's dispatch sequence walks runs of 8 m-tiles over contiguous n-tiles
    // (its wq slice stays hot in its own per-XCD L2 despite the 8x re-read).
    const int bid = blockIdx.x;                 // 0..1375
    const int w   = (bid & 7) * 172 + (bid >> 3);
    const int m0  = (w & 7) * BM;
    const int n0  = (w >> 3) * BN;

    const int wid  = tid >> 6;
    const int lane = tid & 63;
    const int quad = lane >> 4;
    const int lm   = lane & 15;
    const int wm   = (wid >> 1) * 32;
    const int wn   = (wid & 1) * 32;

    // A-DMA geometry: issue j covers rows wid*8 + j*32 .. +8
    const int arow0 = wid * 8 + (lane >> 3);                  // + j*32
    const int acol  = ((lane & 7) ^ ((lane >> 3) & 7)) * 8;   // swizzle on global side
    const int aslot = (lane & 7) * 8;

    // B decode geometry: 2 threads per 32-weight group
    const int gin      = tid >> 1;
    const int half     = tid & 1;
    const int bn_local = gin >> 1;  // 0..63
    const int bkg      = gin & 1;   // k-group within BK
    const int c0       = bkg * 4 + half * 2;
    const int swz      = bn_local & 7;

    auto stageA = [&](int it, int buf) {
#pragma unroll
        for (int j = 0; j < 2; ++j) {
            const int row = arow0 + j * 32;
            async_ld16(&As[buf][(row << 6) + aslot],
                       &xb[(size_t)(m0 + row) * K_TOTAL + it * 64 + acol]);
        }
    };

    // NAMED double-buffer registers (no dynamic indexing -> no scratch)
    int2 w0a, w1a, w2a; float na;
    int2 w0b, w1b, w2b; float nb;

    auto loadNorm = [&](int g) -> float {
        if (mode == 0)      return ((const float*)wnorm)[g];
        else if (mode == 1) return __half2float(((const __half*)wnorm)[g]);
        else                return __builtin_bit_cast(float,
                               (unsigned int)((const unsigned short*)wnorm)[g] << 16);
    };
    auto loadB = [&](int it, int2& w0, int2& w1, int2& w2, float& nrm) {
        const int g    = (n0 + bn_local) * (K_TOTAL / 32) + it * 2 + bkg;
        const int base = g * 12 + half * 6;
        w0 = *(const int2*)&wq[base];
        w1 = *(const int2*)&wq[base + 2];
        w2 = *(const int2*)&wq[base + 4];
        nrm = loadNorm(g);
    };
    auto decodeB = [&](int2 w0, int2 w1, int2 w2, float nrm, int buf) {
        const float a = nrm * (2.0f / 7.0f);
        const float b = -nrm;
        const unsigned int bits0 =
            (unsigned)w0.x | ((unsigned)w0.y << 8) | ((unsigned)w1.x << 16);
        const unsigned int bits1 =
            (unsigned)w1.y | ((unsigned)w2.x << 8) | ((unsigned)w2.y << 16);
        unsigned int packs[8];
#pragma unroll
        for (int t3 = 0; t3 < 2; ++t3) {
            const unsigned int bits = t3 ? bits1 : bits0;
#pragma unroll
            for (int j = 0; j < 4; ++j) {
                const float f0 = fmaf((float)((bits >> (6 * j)) & 7), a, b);
                const float f1 = fmaf((float)((bits >> (6 * j + 3)) & 7), a, b);
                packs[t3 * 4 + j] = pack2_bf16(f0, f1);
            }
        }
        *(uint4*)&Bs[buf][(bn_local << 6) + ((c0 ^ swz) << 3)] =
            make_uint4(packs[0], packs[1], packs[2], packs[3]);
        *(uint4*)&Bs[buf][(bn_local << 6) + (((c0 + 1) ^ swz) << 3)] =
            make_uint4(packs[4], packs[5], packs[6], packs[7]);
    };

    f32x4 acc[2][2];
#pragma unroll
    for (int i = 0; i < 2; ++i)
#pragma unroll
        for (int j = 0; j < 2; ++j) acc[i][j] = (f32x4){0.f, 0.f, 0.f, 0.f};

    auto mfmaTile = [&](const unsigned short* Asb, const unsigned short* Bsb) {
#pragma unroll
        for (int ks = 0; ks < 2; ++ks) {
            const int cswz = (((ks * 4 + quad) ^ (lm & 7)) << 3);
            bf16x8 aF[2], bF[2];
#pragma unroll
            for (int mi = 0; mi < 2; ++mi)
                aF[mi] = *(const bf16x8*)&Asb[((wm + mi * 16 + lm) << 6) + cswz];
#pragma unroll
            for (int ni = 0; ni < 2; ++ni)
                bF[ni] = *(const bf16x8*)&Bsb[((wn + ni * 16 + lm) << 6) + cswz];
#pragma unroll
            for (int mi = 0; mi < 2; ++mi)
#pragma unroll
                for (int ni = 0; ni < 2; ++ni)
                    acc[mi][ni] = __builtin_amdgcn_mfma_f32_16x16x32_bf16(
                        aF[mi], bF[ni], acc[mi][ni], 0, 0, 0);
        }
    };

    // prologue: stage tile 0 into buf0 (setA), prefetch packed tile 1 (setB)
    stageA(0, 0);
    loadB(0, w0a, w1a, w2a, na);
    decodeB(w0a, w1a, w2a, na, 0);
    loadB(1, w0b, w1b, w2b, nb);
    __syncthreads();  // drains A-DMA(0) + LDS writes

    // manually unrolled x2: global issues first (max cover before barrier drain)
    for (int it = 0; it < NT; it += 2) {
        // ---- sub-iter 0: compute buf0 (tile it)
        if (it + 1 < NT) stageA(it + 1, 1);
        if (it + 2 < NT) loadB(it + 2, w0a, w1a, w2a, na);
        if (it + 1 < NT) decodeB(w0b, w1b, w2b, nb, 1);   // setB holds tile it+1
        mfmaTile(As[0], Bs[0]);
        __syncthreads();

        // ---- sub-iter 1: compute buf1 (tile it+1)
        if (it + 2 < NT) stageA(it + 2, 0);
        if (it + 3 < NT) loadB(it + 3, w0b, w1b, w2b, nb);
        if (it + 2 < NT) decodeB(w0a, w1a, w2a, na, 0);   // setA holds tile it+2
        mfmaTile(As[1], Bs[1]);
        __syncthreads();
    }

    // epilogue: C/D layout col=lane&15, row=quad*4+reg
#pragma unroll
    for (int ni = 0; ni < 2; ++ni) {
        const int o  = n0 + wn + ni * 16 + lm;
        const float bv = bias[o];
#pragma unroll
        for (int mi = 0; mi < 2; ++mi) {
#pragma unroll
            for (int r = 0; r < 4; ++r) {
                const int m = m0 + wm + mi * 16 + quad * 4 + r;
                out[m * N_TOTAL + o] = acc[mi][ni][r] + bv;
            }
        }
    }
}

// ---------------- fallback (r2 kernel) if ws too small ----------------
__global__ void __launch_bounds__(256)
l3b_gemm_kernel(const float* __restrict__ x, const int* __restrict__ wq,
                const void* __restrict__ wnorm, const float* __restrict__ bias,
                float* __restrict__ out, const int* __restrict__ mode_ptr)
{
    __shared__ unsigned short As[128 * LDK];
    __shared__ unsigned short Bs[64 * LDK];

    const int mode = *mode_ptr;
    const int tid  = threadIdx.x;
    const int m0   = blockIdx.y * 128;
    const int n0   = blockIdx.x * 64;
    const int wid  = tid >> 6;
    const int lane = tid & 63;
    const int quad = lane >> 4;
    const int lm   = lane & 15;
    const int wm   = (wid >> 1) * 64;
    const int wn   = (wid & 1) * 32;

    f32x4 acc[4][2];
#pragma unroll
    for (int i = 0; i < 4; ++i)
#pragma unroll
        for (int j = 0; j < 2; ++j) acc[i][j] = (f32x4){0.f, 0.f, 0.f, 0.f};

    const int ar = tid >> 4;
    const int ac = (tid & 15) * 4;
    const int gin      = tid >> 1;
    const int half     = tid & 1;
    const int bn_local = gin >> 1;
    const int bkg      = gin & 1;

    for (int it = 0; it < NT; ++it) {
        const int k0 = it * BK;
        __syncthreads();
#pragma unroll
        for (int p = 0; p < 8; ++p) {
            const int row = p * 16 + ar;
            const float4 v = *(const float4*)&x[(m0 + row) * K_TOTAL + k0 + ac];
            *(uint2*)&As[row * LDK + ac] =
                make_uint2(pack2_bf16(v.x, v.y), pack2_bf16(v.z, v.w));
        }
        {
            const int g    = (n0 + bn_local) * (K_TOTAL / 32) + it * 2 + bkg;
            const int base = g * 12 + half * 6;
            const int2 w0 = *(const int2*)&wq[base];
            const int2 w1 = *(const int2*)&wq[base + 2];
            const int2 w2 = *(const int2*)&wq[base + 4];
            float nrm;
            if (mode == 0)      nrm = ((const float*)wnorm)[g];
            else if (mode == 1) nrm = __half2float(((const __half*)wnorm)[g]);
            else                nrm = __builtin_bit_cast(float,
                                    (unsigned int)((const unsigned short*)wnorm)[g] << 16);
            const float a = nrm * (2.0f / 7.0f);
            const float b = -nrm;
            const unsigned int bits0 =
                (unsigned)w0.x | ((unsigned)w0.y << 8) | ((unsigned)w1.x << 16);
            const unsigned int bits1 =
                (unsigned)w1.y | ((unsigned)w2.x << 8) | ((unsigned)w2.y << 16);
            unsigned int packs[8];
#pragma unroll
            for (int t3 = 0; t3 < 2; ++t3) {
                const unsigned int bits = t3 ? bits1 : bits0;
#pragma unroll
                for (int j = 0; j < 4; ++j) {
                    const float f0 = fmaf((float)((bits >> (6 * j)) & 7), a, b);
                    const float f1 = fmaf((float)((bits >> (6 * j + 3)) & 7), a, b);
                    packs[t3 * 4 + j] = pack2_bf16(f0, f1);
                }
            }
            unsigned int* dst = (unsigned int*)&Bs[bn_local * LDK + bkg * 32 + half * 16];
            *(uint4*)dst       = make_uint4(packs[0], packs[1], packs[2], packs[3]);
            *(uint4*)(dst + 4) = make_uint4(packs[4], packs[5], packs[6], packs[7]);
        }
        __syncthreads();
#pragma unroll
        for (int ks = 0; ks < 2; ++ks) {
            const int kb = ks * 32 + quad * 8;
            bf16x8 aF[4], bF[2];
#pragma unroll
            for (int mi = 0; mi < 4; ++mi)
                aF[mi] = *(const bf16x8*)&As[(wm + mi * 16 + lm) * LDK + kb];
#pragma unroll
            for (int ni = 0; ni < 2; ++ni)
                bF[ni] = *(const bf16x8*)&Bs[(wn + ni * 16 + lm) * LDK + kb];
#pragma unroll
            for (int mi = 0; mi < 4; ++mi)
#pragma unroll
                for (int ni = 0; ni < 2; ++ni)
                    acc[mi][ni] = __builtin_amdgcn_mfma_f32_16x16x32_bf16(
                        aF[mi], bF[ni], acc[mi][ni], 0, 0, 0);
        }
    }
#pragma unroll
    for (int ni = 0; ni < 2; ++ni) {
        const int o  = n0 + wn + ni * 16 + lm;
        const float bv = bias[o];
#pragma unroll
        for (int mi = 0; mi < 4; ++mi)
#pragma unroll
            for (int r = 0; r < 4; ++r) {
                const int m = m0 + wm + mi * 16 + quad * 4 + r;
                out[m * N_TOTAL + o] = acc[mi][ni][r] + bv;
            }
    }
}

extern "C" void kernel_launch(void* const* d_in, const int* in_sizes, int n_in,
                              void* d_out, int out_size, void* d_ws, size_t ws_size,
                              hipStream_t stream) {
    const float* x    = (const float*)d_in[0];
    const int*   wq   = (const int*)d_in[1];
    const void*  wn   = d_in[2];
    const float* bias = (const float*)d_in[3];
    float* out = (float*)d_out;
    int* mode = (int*)d_ws;

    detect_norm_dtype<<<1, 64, 0, stream>>>(wn, mode);

    const size_t need = 256 + (size_t)M_TOTAL * K_TOTAL * 2;
    if (ws_size >= need) {
        unsigned short* xb = (unsigned short*)((char*)d_ws + 256);
        convert_x_kernel<<<(M_TOTAL * K_TOTAL / 4) / 256, 256, 0, stream>>>(x, xb);
        l3b_gemm_pipe<<<(M_TOTAL / BM) * (N_TOTAL / BN), 256, 0, stream>>>(
            xb, wq, wn, bias, out, mode);
    } else {
        dim3 grid(N_TOTAL / 64, M_TOTAL / 128);
        l3b_gemm_kernel<<<grid, 256, 0, stream>>>(x, wq, wn, bias, out, mode);
    }
}

// Round 6
// 198.347 us; speedup vs baseline: 1.2246x; 1.2246x over previous
//
#include <hip/hip_runtime.h>
#include <hip/hip_fp16.h>

#define M_TOTAL 512
#define N_TOTAL 11008
#define K_TOTAL 4096
#define BM 128
#define BN 64
#define BK 64
#define NT (K_TOTAL / BK)  // 64
#define LDK 72             // fallback kernel's padded stride

typedef short bf16x8 __attribute__((ext_vector_type(8)));
typedef float f32x4 __attribute__((ext_vector_type(4)));

// pack two fp32 into two bf16 (round-half-up) -> uint32 (f0 in low 16)
__device__ __forceinline__ unsigned int pack2_bf16(float f0, float f1) {
    unsigned int u0 = __builtin_bit_cast(unsigned int, f0) + 0x8000u;
    unsigned int u1 = __builtin_bit_cast(unsigned int, f1) + 0x8000u;
    return (u0 >> 16) | (u1 & 0xFFFF0000u);
}

// async global->LDS 16B DMA (LDS dest must be wave-uniform base + lane*16)
__device__ __forceinline__ void async_ld16(void* lds, const void* g) {
    __builtin_amdgcn_global_load_lds(
        (const __attribute__((address_space(1))) unsigned int*)g,
        (__attribute__((address_space(3))) unsigned int*)lds, 16, 0, 0);
}

// Per-wave inline dtype detection for weight_norm: 0=f32, 1=f16, 2=bf16.
// All lanes probe one element; ballot makes the result wave-uniform (SGPR),
// so downstream mode branches are scalar. ~200 cyc, L2-hot after block 0.
__device__ __forceinline__ int detect_mode_wave(const void* __restrict__ wn) {
    const int lane = threadIdx.x & 63;
    const unsigned short* u16 = (const unsigned short*)wn;
    const float* f32p = (const float*)wn;
    const float vb = __builtin_bit_cast(float, (unsigned int)u16[lane] << 16);
    const float vh = __half2float(__builtin_bit_cast(__half, u16[lane]));
    const float vf = f32p[lane];
    const unsigned long long mb = __ballot(vb > 0.005f && vb < 0.12f);
    const unsigned long long mh = __ballot(vh > 0.005f && vh < 0.12f);
    (void)vf;
    return (mb == ~0ull) ? 2 : ((mh == ~0ull) ? 1 : 0);
}

// one-shot x fp32 -> bf16
__global__ void __launch_bounds__(256)
convert_x_kernel(const float* __restrict__ x, unsigned short* __restrict__ xb) {
    const int i = (blockIdx.x * 256 + threadIdx.x) * 4;
    const float4 v = *(const float4*)&x[i];
    *(uint2*)&xb[i] = make_uint2(pack2_bf16(v.x, v.y), pack2_bf16(v.z, v.w));
}

// -------- pipelined main kernel: 512 threads (8 waves), 128x64 tile --------
__global__ void __launch_bounds__(512, 6)
l3b_gemm_pipe(const unsigned short* __restrict__ xb, const int* __restrict__ wq,
              const void* __restrict__ wnorm, const float* __restrict__ bias,
              float* __restrict__ out)
{
    // XOR-swizzled, unpadded: row stride 64 el (128 B); 16-B chunk p of row r
    // holds logical chunk p ^ (r & 7).
    __shared__ unsigned short As[2][BM * 64];  // 16 KB x2
    __shared__ unsigned short Bs[2][BN * 64];  // 8 KB x2  -> 48 KB (3 blocks/CU)

    const int tid  = threadIdx.x;
    const int mode = detect_mode_wave(wnorm);

    // XCD swizzle (kept from R5: FETCH 148->73 MB): each XCD walks ~22
    // contiguous n-tiles x 4 m-tiles, wq slice (~2.2 MB) stays in its L2.
    const int bid = blockIdx.x;                 // 0..687
    const int w   = (bid & 7) * 86 + (bid >> 3);
    const int m0  = (w & 3) * BM;
    const int n0  = (w >> 2) * BN;

    const int wid  = tid >> 6;   // 0..7
    const int lane = tid & 63;
    const int quad = lane >> 4;
    const int lm   = lane & 15;
    const int wm   = (wid >> 1) * 32;   // 0,32,64,96
    const int wn_  = (wid & 1) * 32;    // 0,32

    // A-DMA: wave wid stages rows wid*8+(lane>>3) + j*64, j=0..1
    const int arow0 = wid * 8 + (lane >> 3);
    const int acol  = ((lane & 7) ^ ((lane >> 3) & 7)) * 8;  // swizzle on global side
    const int aslot = (lane & 7) * 8;

    // B decode: 1 thread per 8 weights (512 thr = 128 groups x 4 subs)
    const int gl   = tid >> 2;     // group-in-tile 0..127
    const int sub  = tid & 3;      // 8-weight chunk within group
    const int bn_l = gl >> 1;      // 0..63
    const int kg   = gl & 1;       // k-half of the 64-el row
    const int ldsB = (bn_l << 6) + ((((kg * 4 + sub)) ^ (bn_l & 7)) << 3);

    auto stageA = [&](int it, int buf) {
#pragma unroll
        for (int j = 0; j < 2; ++j) {
            const int row = arow0 + j * 64;
            async_ld16(&As[buf][(row << 6) + aslot],
                       &xb[(size_t)(m0 + row) * K_TOTAL + it * 64 + acol]);
        }
    };

    auto loadNorm = [&](int g) -> float {
        if (mode == 0)      return ((const float*)wnorm)[g];
        else if (mode == 1) return __half2float(((const __half*)wnorm)[g]);
        else                return __builtin_bit_cast(float,
                               (unsigned int)((const unsigned short*)wnorm)[g] << 16);
    };
    auto loadB = [&](int it, int& b0, int& b1, int& b2, float& nrm) {
        const int g    = (n0 + bn_l) * (K_TOTAL / 32) + it * 2 + kg;
        const int base = g * 12 + sub * 3;
        b0 = wq[base]; b1 = wq[base + 1]; b2 = wq[base + 2];
        nrm = loadNorm(g);
    };
    auto decodeB = [&](int b0, int b1, int b2, float nrm, int buf) {
        const float a = nrm * (2.0f / 7.0f);
        const float b = -nrm;
        const unsigned int bits =
            (unsigned)b0 | ((unsigned)b1 << 8) | ((unsigned)b2 << 16);
        unsigned int packs[4];
#pragma unroll
        for (int j = 0; j < 4; ++j) {
            const float f0 = fmaf((float)((bits >> (6 * j)) & 7), a, b);
            const float f1 = fmaf((float)((bits >> (6 * j + 3)) & 7), a, b);
            packs[j] = pack2_bf16(f0, f1);
        }
        *(uint4*)&Bs[buf][ldsB] = make_uint4(packs[0], packs[1], packs[2], packs[3]);
    };

    f32x4 acc[2][2];
#pragma unroll
    for (int i = 0; i < 2; ++i)
#pragma unroll
        for (int j = 0; j < 2; ++j) acc[i][j] = (f32x4){0.f, 0.f, 0.f, 0.f};

    auto mfmaTile = [&](const unsigned short* Asb, const unsigned short* Bsb) {
#pragma unroll
        for (int ks = 0; ks < 2; ++ks) {
            const int cswz = (((ks * 4 + quad) ^ (lm & 7)) << 3);
            bf16x8 aF[2], bF[2];
#pragma unroll
            for (int mi = 0; mi < 2; ++mi)
                aF[mi] = *(const bf16x8*)&Asb[((wm + mi * 16 + lm) << 6) + cswz];
#pragma unroll
            for (int ni = 0; ni < 2; ++ni)
                bF[ni] = *(const bf16x8*)&Bsb[((wn_ + ni * 16 + lm) << 6) + cswz];
#pragma unroll
            for (int mi = 0; mi < 2; ++mi)
#pragma unroll
                for (int ni = 0; ni < 2; ++ni)
                    acc[mi][ni] = __builtin_amdgcn_mfma_f32_16x16x32_bf16(
                        aF[mi], bF[ni], acc[mi][ni], 0, 0, 0);
        }
    };

    // named double-buffer registers (no dynamic indexing -> no scratch)
    int b0a, b1a, b2a; float na;
    int b0b, b1b, b2b; float nb;

    // prologue
    stageA(0, 0);
    loadB(0, b0a, b1a, b2a, na);
    decodeB(b0a, b1a, b2a, na, 0);
    loadB(1, b0b, b1b, b2b, nb);
    __syncthreads();

    // unrolled x2: global issues first (max cover before the barrier drain)
    for (int it = 0; it < NT; it += 2) {
        if (it + 1 < NT) stageA(it + 1, 1);
        if (it + 2 < NT) loadB(it + 2, b0a, b1a, b2a, na);
        if (it + 1 < NT) decodeB(b0b, b1b, b2b, nb, 1);
        mfmaTile(As[0], Bs[0]);
        __syncthreads();

        if (it + 2 < NT) stageA(it + 2, 0);
        if (it + 3 < NT) loadB(it + 3, b0b, b1b, b2b, nb);
        if (it + 2 < NT) decodeB(b0a, b1a, b2a, na, 0);
        mfmaTile(As[1], Bs[1]);
        __syncthreads();
    }

    // epilogue: C/D layout col=lane&15, row=quad*4+reg
#pragma unroll
    for (int ni = 0; ni < 2; ++ni) {
        const int o  = n0 + wn_ + ni * 16 + lm;
        const float bv = bias[o];
#pragma unroll
        for (int mi = 0; mi < 2; ++mi) {
#pragma unroll
            for (int r = 0; r < 4; ++r) {
                const int m = m0 + wm + mi * 16 + quad * 4 + r;
                out[m * N_TOTAL + o] = acc[mi][ni][r] + bv;
            }
        }
    }
}

// ---------------- fallback (r2 kernel) if ws too small ----------------
__global__ void __launch_bounds__(256)
l3b_gemm_kernel(const float* __restrict__ x, const int* __restrict__ wq,
                const void* __restrict__ wnorm, const float* __restrict__ bias,
                float* __restrict__ out)
{
    __shared__ unsigned short As[128 * LDK];
    __shared__ unsigned short Bs[64 * LDK];

    const int mode = detect_mode_wave(wnorm);
    const int tid  = threadIdx.x;
    const int m0   = blockIdx.y * 128;
    const int n0   = blockIdx.x * 64;
    const int wid  = tid >> 6;
    const int lane = tid & 63;
    const int quad = lane >> 4;
    const int lm   = lane & 15;
    const int wm   = (wid >> 1) * 64;
    const int wn   = (wid & 1) * 32;

    f32x4 acc[4][2];
#pragma unroll
    for (int i = 0; i < 4; ++i)
#pragma unroll
        for (int j = 0; j < 2; ++j) acc[i][j] = (f32x4){0.f, 0.f, 0.f, 0.f};

    const int ar = tid >> 4;
    const int ac = (tid & 15) * 4;
    const int gin      = tid >> 1;
    const int half     = tid & 1;
    const int bn_local = gin >> 1;
    const int bkg      = gin & 1;

    for (int it = 0; it < NT; ++it) {
        const int k0 = it * BK;
        __syncthreads();
#pragma unroll
        for (int p = 0; p < 8; ++p) {
            const int row = p * 16 + ar;
            const float4 v = *(const float4*)&x[(m0 + row) * K_TOTAL + k0 + ac];
            *(uint2*)&As[row * LDK + ac] =
                make_uint2(pack2_bf16(v.x, v.y), pack2_bf16(v.z, v.w));
        }
        {
            const int g    = (n0 + bn_local) * (K_TOTAL / 32) + it * 2 + bkg;
            const int base = g * 12 + half * 6;
            const int2 w0 = *(const int2*)&wq[base];
            const int2 w1 = *(const int2*)&wq[base + 2];
            const int2 w2 = *(const int2*)&wq[base + 4];
            float nrm;
            if (mode == 0)      nrm = ((const float*)wnorm)[g];
            else if (mode == 1) nrm = __half2float(((const __half*)wnorm)[g]);
            else                nrm = __builtin_bit_cast(float,
                                    (unsigned int)((const unsigned short*)wnorm)[g] << 16);
            const float a = nrm * (2.0f / 7.0f);
            const float b = -nrm;
            const unsigned int bits0 =
                (unsigned)w0.x | ((unsigned)w0.y << 8) | ((unsigned)w1.x << 16);
            const unsigned int bits1 =
                (unsigned)w1.y | ((unsigned)w2.x << 8) | ((unsigned)w2.y << 16);
            unsigned int packs[8];
#pragma unroll
            for (int t3 = 0; t3 < 2; ++t3) {
                const unsigned int bits = t3 ? bits1 : bits0;
#pragma unroll
                for (int j = 0; j < 4; ++j) {
                    const float f0 = fmaf((float)((bits >> (6 * j)) & 7), a, b);
                    const float f1 = fmaf((float)((bits >> (6 * j + 3)) & 7), a, b);
                    packs[t3 * 4 + j] = pack2_bf16(f0, f1);
                }
            }
            unsigned int* dst = (unsigned int*)&Bs[bn_local * LDK + bkg * 32 + half * 16];
            *(uint4*)dst       = make_uint4(packs[0], packs[1], packs[2], packs[3]);
            *(uint4*)(dst + 4) = make_uint4(packs[4], packs[5], packs[6], packs[7]);
        }
        __syncthreads();
#pragma unroll
        for (int ks = 0; ks < 2; ++ks) {
            const int kb = ks * 32 + quad * 8;
            bf16x8 aF[4], bF[2];
#pragma unroll
            for (int mi = 0; mi < 4; ++mi)
                aF[mi] = *(const bf16x8*)&As[(wm + mi * 16 + lm) * LDK + kb];
#pragma unroll
            for (int ni = 0; ni < 2; ++ni)
                bF[ni] = *(const bf16x8*)&Bs[(wn + ni * 16 + lm) * LDK + kb];
#pragma unroll
            for (int mi = 0; mi < 4; ++mi)
#pragma unroll
                for (int ni = 0; ni < 2; ++ni)
                    acc[mi][ni] = __builtin_amdgcn_mfma_f32_16x16x32_bf16(
                        aF[mi], bF[ni], acc[mi][ni], 0, 0, 0);
        }
    }
#pragma unroll
    for (int ni = 0; ni < 2; ++ni) {
        const int o  = n0 + wn + ni * 16 + lm;
        const float bv = bias[o];
#pragma unroll
        for (int mi = 0; mi < 4; ++mi)
#pragma unroll
            for (int r = 0; r < 4; ++r) {
                const int m = m0 + wm + mi * 16 + quad * 4 + r;
                out[m * N_TOTAL + o] = acc[mi][ni][r] + bv;
            }
    }
}

extern "C" void kernel_launch(void* const* d_in, const int* in_sizes, int n_in,
                              void* d_out, int out_size, void* d_ws, size_t ws_size,
                              hipStream_t stream) {
    const float* x    = (const float*)d_in[0];
    const int*   wq   = (const int*)d_in[1];
    const void*  wn   = d_in[2];
    const float* bias = (const float*)d_in[3];
    float* out = (float*)d_out;

    const size_t need = 256 + (size_t)M_TOTAL * K_TOTAL * 2;
    if (ws_size >= need) {
        unsigned short* xb = (unsigned short*)((char*)d_ws + 256);
        convert_x_kernel<<<(M_TOTAL * K_TOTAL / 4) / 256, 256, 0, stream>>>(x, xb);
        l3b_gemm_pipe<<<(M_TOTAL / BM) * (N_TOTAL / BN), 512, 0, stream>>>(
            xb, wq, wn, bias, out);
    } else {
        dim3 grid(N_TOTAL / 64, M_TOTAL / 128);
        l3b_gemm_kernel<<<grid, 256, 0, stream>>>(x, wq, wn, bias, out);
    }
}